// Round 10
// baseline (102.891 us; speedup 1.0000x reference)
//
#include <hip/hip_runtime.h>

typedef unsigned short u16;
typedef __bf16 bf16x8 __attribute__((ext_vector_type(8)));
typedef float  f32x4  __attribute__((ext_vector_type(4)));
typedef u16    u16x4  __attribute__((ext_vector_type(4)));

#define HH   16
#define DHH  64
#define SEQL 2048
#define NB   2
#define BHN  (NB * HH)   // 32
#define SCLF 0.1803368801111204f   // 0.125 * log2(e)

static __device__ __forceinline__ u16 f2bf(float f) {
    return __builtin_bit_cast(u16, (__bf16)f);
}

// direct global->LDS DMA, 16B per lane; LDS dest = wave-uniform base + lane*16
static __device__ __forceinline__ void gload_lds16(const void* g, void* l) {
    __builtin_amdgcn_global_load_lds(
        (const __attribute__((address_space(1))) unsigned int*)g,
        (__attribute__((address_space(3))) unsigned int*)l, 16, 0, 0);
}

// ---------------------------------------------------------------------------
// Kernel 0: one-time W f32 -> bf16 pre-cast.  Wb layout: [m][h][e][d] bf16.
// Wq is pre-scaled by SCLF so QK^T lands directly in the exp2 domain.
// ---------------------------------------------------------------------------
__global__ __launch_bounds__(256) void wconv_kernel(
    const float* __restrict__ Wq, const float* __restrict__ Wk,
    const float* __restrict__ Wv, u16* __restrict__ Wb)
{
    const int m = blockIdx.y;
    const float* W = (m == 0) ? Wq : (m == 1) ? Wk : Wv;
    const float s = (m == 0) ? SCLF : 1.0f;
    const int i = (blockIdx.x * 256 + threadIdx.x) * 4;   // 65536 f32 per matrix
    float4 v = *reinterpret_cast<const float4*>(W + i);
    u16x4 o = { f2bf(v.x * s), f2bf(v.y * s), f2bf(v.z * s), f2bf(v.w * s) };
    *reinterpret_cast<u16x4*>(Wb + (size_t)m * 65536 + i) = o;
}

// ---------------------------------------------------------------------------
// Kernel 1: per-head QKV projection.  x[B,S,D] f32 -> Q,K bf16 [bh][S][64],
// V^T bf16 [bh][64][S].  One block = 64 rows x 1 head, 4 waves x 16 rows.
// All global stores coalesced 16B via the LDS repack tile.
// ---------------------------------------------------------------------------
__global__ __launch_bounds__(256) void qkv_kernel(
    const float* __restrict__ x, const u16* __restrict__ Wb,
    const float* __restrict__ bq, const float* __restrict__ bk,
    const float* __restrict__ bv,
    u16* __restrict__ Qws, u16* __restrict__ Kws, u16* __restrict__ Vtws)
{
    const int h   = blockIdx.y;
    const int r0  = blockIdx.x * 64;          // row in [0, B*S)
    const int tid = threadIdx.x;
    const int w   = tid >> 6;
    const int l   = tid & 63;
    const int c   = l & 15;
    const int g   = l >> 4;

    __shared__ u16 vt[64 * 72];               // repack tile (reused Q,K,V)

    bf16x8 xa[2];
    {
        const float* xp = x + (size_t)(r0 + w * 16 + c) * 1024 + h * 64 + g * 8;
        #pragma unroll
        for (int kh = 0; kh < 2; ++kh) {
            float4 lo = *reinterpret_cast<const float4*>(xp + kh * 32);
            float4 hi = *reinterpret_cast<const float4*>(xp + kh * 32 + 4);
            bf16x8 f;
            f[0]=(__bf16)lo.x; f[1]=(__bf16)lo.y; f[2]=(__bf16)lo.z; f[3]=(__bf16)lo.w;
            f[4]=(__bf16)hi.x; f[5]=(__bf16)hi.y; f[6]=(__bf16)hi.z; f[7]=(__bf16)hi.w;
            xa[kh] = f;
        }
    }

    const int b      = r0 >> 11;              // / SEQL
    const int s_base = r0 & (SEQL - 1);
    const int bh     = b * HH + h;

    const float* bs[3] = {bq + h * 64, bk + h * 64, bv + h * 64};

    #pragma unroll
    for (int m = 0; m < 3; ++m) {
        const u16*   W    = Wb + (size_t)m * 65536 + h * 4096;
        const float* bias = bs[m];
        const float  bscl = (m == 0) ? SCLF : 1.0f;
        f32x4 acc[4];
        #pragma unroll
        for (int ct = 0; ct < 4; ++ct) {
            acc[ct][0] = 0.f; acc[ct][1] = 0.f; acc[ct][2] = 0.f; acc[ct][3] = 0.f;
        }
        #pragma unroll
        for (int kh = 0; kh < 2; ++kh) {
            #pragma unroll
            for (int ct = 0; ct < 4; ++ct) {
                bf16x8 wf = *reinterpret_cast<const bf16x8*>(
                    W + (ct * 16 + c) * 64 + kh * 32 + g * 8);
                acc[ct] = __builtin_amdgcn_mfma_f32_16x16x32_bf16(xa[kh], wf, acc[ct], 0, 0, 0);
            }
        }
        // C layout: col(e) = ct*16+c, row(s within 16) = g*4 + r
        if (m < 2) {
            if (m == 1) __syncthreads();
            #pragma unroll
            for (int ct = 0; ct < 4; ++ct) {
                float bb = bias[ct * 16 + c] * bscl;
                #pragma unroll
                for (int r = 0; r < 4; ++r)
                    vt[(w * 16 + g * 4 + r) * 72 + ct * 16 + c] = f2bf(acc[ct][r] + bb);
            }
            __syncthreads();
            {
                const int d  = tid >> 2;
                const int s0 = (tid & 3) * 16;
                u16* outp = (m == 0 ? Qws : Kws) +
                            ((size_t)bh * SEQL + s_base + d) * 64 + s0;
                uint4 v0 = *reinterpret_cast<const uint4*>(&vt[d * 72 + s0]);
                uint4 v1 = *reinterpret_cast<const uint4*>(&vt[d * 72 + s0 + 8]);
                *reinterpret_cast<uint4*>(outp)     = v0;
                *reinterpret_cast<uint4*>(outp + 8) = v1;
            }
        } else {
            __syncthreads();
            #pragma unroll
            for (int ct = 0; ct < 4; ++ct) {
                float bb = bias[ct * 16 + c];
                u16x4 pb;
                #pragma unroll
                for (int r = 0; r < 4; ++r)
                    pb[r] = f2bf(acc[ct][r] + bb);
                *reinterpret_cast<u16x4*>(&vt[(ct * 16 + c) * 72 + w * 16 + g * 4]) = pb;
            }
            __syncthreads();
            {
                const int d  = tid >> 2;
                const int s0 = (tid & 3) * 16;
                u16* vp = Vtws + ((size_t)bh * 64 + d) * SEQL + s_base + s0;
                uint4 v0 = *reinterpret_cast<const uint4*>(&vt[d * 72 + s0]);
                uint4 v1 = *reinterpret_cast<const uint4*>(&vt[d * 72 + s0 + 8]);
                *reinterpret_cast<uint4*>(vp)     = v0;
                *reinterpret_cast<uint4*>(vp + 8) = v1;
            }
        }
    }
}

// ---------------------------------------------------------------------------
// Kernel 2: flash attention.  One block = 128 q-rows of one (b,h); 4 waves x
// 32 q-rows.  S^T = K*Q^T (q lane-local, exp2 domain), online softmax,
// O^T = V^T*P^T.  K tiles double-buffered in LDS (global_load_lds, shared by
// all 4 waves).  R10: V fragments loaded DIRECTLY from global (L2-resident;
// staging was pure overhead) with the T15 A/B register rotation — consumed
// next tile-step, so the end-of-iter barrier's vmcnt drain gives a full body
// of latency cover.  __launch_bounds__(256,2): grid caps us at 2 waves/SIMD
// anyway, so allow up to 256 VGPR for the held V/P prev-state.
// ---------------------------------------------------------------------------
__global__ __launch_bounds__(256, 2) void attn_kernel(
    const u16* __restrict__ Qws, const u16* __restrict__ Kws,
    const u16* __restrict__ Vtws, float* __restrict__ out)
{
    // XCD-chunk swizzle: 512 blocks -> each XCD gets 64 consecutive logical
    // blocks = 4 whole heads (K/V stay in that XCD's L2).
    const int p     = blockIdx.x;
    const int lid   = (p & 7) * 64 + (p >> 3);
    const int qtile = lid & 15;
    const int bh    = lid >> 4;
    const int b     = bh >> 4;
    const int h     = bh & 15;

    const int tid = threadIdx.x;
    const int w   = tid >> 6;
    const int l   = tid & 63;
    const int c   = l & 15;
    const int g   = l >> 4;
    const int q0  = qtile * 128 + w * 32;

    __shared__ u16 k_lds[2][64 * 64];         // [buf][key_local][dh], swizzled
    __shared__ u16 plds_all[4 * 32 * 64];     // per-wave 4KB P buffer
    char* pbase = reinterpret_cast<char*>(plds_all + w * (32 * 64));

    const u16* Kb = Kws  + (size_t)bh * SEQL * 64;
    const u16* Vb = Vtws + (size_t)bh * 64 * SEQL;

    const int rs8 = l >> 3;                   // 0..7
    const int sx  = (l & 7) ^ rs8;            // inverse-swizzled source slot

    #define STAGE(bb, k0)                                                     \
    {   _Pragma("unroll")                                                     \
        for (int a = 0; a < 2; ++a) {                                         \
            const int rbase = w * 16 + a * 8;                                 \
            const int r     = rbase + rs8;                                    \
            gload_lds16(Kb + (size_t)((k0) + r) * 64 + sx * 8,                \
                        &k_lds[bb][rbase * 64]);                              \
        }                                                                     \
    }

    // Q fragments (B-operand of S^T): Q[q0+qt*16+c][kh*32+g*8 ..+8]
    bf16x8 qf[2][2];
    #pragma unroll
    for (int qt = 0; qt < 2; ++qt)
        #pragma unroll
        for (int kh = 0; kh < 2; ++kh)
            qf[qt][kh] = *reinterpret_cast<const bf16x8*>(
                Qws + ((size_t)bh * SEQL + q0 + qt * 16 + c) * 64 + kh * 32 + g * 8);

    const f32x4 zero4 = {0.f, 0.f, 0.f, 0.f};
    bf16x8 ones8;
    #pragma unroll
    for (int j = 0; j < 8; ++j) ones8[j] = __builtin_bit_cast(__bf16, (u16)0x3F80);

    f32x4 acc[4][2];
    #pragma unroll
    for (int dt = 0; dt < 4; ++dt)
        #pragma unroll
        for (int qt = 0; qt < 2; ++qt) acc[dt][qt] = zero4;
    float mrow[2] = {-1e30f, -1e30f};
    float lrow[2] = {0.f, 0.f};

    const int rdoff = ((g ^ (c & 7)) * 8);    // swizzled K read slot (elems)

    // A/B named prev-state (kept in registers across the barrier)
    bf16x8 vfA[8], vfB[8];
    bf16x8 pfA[2][2], pfB[2][2];
    f32x4  suA[2], suB[2];

    STAGE(0, 0);
    __syncthreads();

    // one tile-step: V(t) global loads -> QK(t) -> PV(t-1) -> softmax(t)
    auto body = [&](bf16x8 (&vfC)[8], bf16x8 (&pfC)[2][2], f32x4 (&suC)[2],
                    bf16x8 (&vfP)[8], bf16x8 (&pfP)[2][2], f32x4 (&suP)[2],
                    int t, bool has_prev) {
        const int cur = t & 1;
        const int k0  = t * 64;

        // ---- V(t) fragments straight from global (L2-resident).  Consumed
        //      next tile-step; the end-of-iter barrier drain covers them.
        #pragma unroll
        for (int dt = 0; dt < 4; ++dt) {
            const u16* vp = Vb + (size_t)(dt * 16 + c) * SEQL + k0 + g * 8;
            vfC[dt * 2]     = *reinterpret_cast<const bf16x8*>(vp);
            vfC[dt * 2 + 1] = *reinterpret_cast<const bf16x8*>(vp + 32);
        }

        // ---- issue next K tile's staging; lands during this compute phase
        if (t + 1 < SEQL / 64) STAGE(cur ^ 1, (t + 1) * 64);

        // ---- S^T = K * Q^T (exp2 domain; Q pre-scaled)
        f32x4 st[4][2];
        __builtin_amdgcn_s_setprio(1);
        #pragma unroll
        for (int kt = 0; kt < 4; ++kt) {
            const int e0 = (kt * 16 + c) * 64 + rdoff;
            bf16x8 ka0 = *reinterpret_cast<const bf16x8*>(&k_lds[cur][e0]);
            bf16x8 ka1 = *reinterpret_cast<const bf16x8*>(&k_lds[cur][e0 ^ 32]);
            #pragma unroll
            for (int qt = 0; qt < 2; ++qt) {
                st[kt][qt] = __builtin_amdgcn_mfma_f32_16x16x32_bf16(ka0, qf[qt][0], zero4,      0, 0, 0);
                st[kt][qt] = __builtin_amdgcn_mfma_f32_16x16x32_bf16(ka1, qf[qt][1], st[kt][qt], 0, 0, 0);
            }
        }
        // ---- PV(t-1) from registers: matrix pipe stays busy while the
        //      softmax below runs on the VALU (no data dependence).
        if (has_prev) {
            #pragma unroll
            for (int dt = 0; dt < 4; ++dt)
                #pragma unroll
                for (int qt = 0; qt < 2; ++qt) {
                    acc[dt][qt] = __builtin_amdgcn_mfma_f32_16x16x32_bf16(vfP[dt*2],   pfP[qt][0], acc[dt][qt], 0, 0, 0);
                    acc[dt][qt] = __builtin_amdgcn_mfma_f32_16x16x32_bf16(vfP[dt*2+1], pfP[qt][1], acc[dt][qt], 0, 0, 0);
                }
        }
        __builtin_amdgcn_s_setprio(0);

        // ---- online softmax (q-row lane-local; sums ride the MFMA pipe)
        #pragma unroll
        for (int qt = 0; qt < 2; ++qt) {
            if (has_prev) lrow[qt] += suP[qt][0];   // sum of P(t-1) before alpha(t)

            float a0 = fmaxf(st[0][qt][0], st[0][qt][1]);
            float a1 = fmaxf(st[0][qt][2], st[0][qt][3]);
            float a2 = fmaxf(st[1][qt][0], st[1][qt][1]);
            float a3 = fmaxf(st[1][qt][2], st[1][qt][3]);
            float a4 = fmaxf(st[2][qt][0], st[2][qt][1]);
            float a5 = fmaxf(st[2][qt][2], st[2][qt][3]);
            float a6 = fmaxf(st[3][qt][0], st[3][qt][1]);
            float a7 = fmaxf(st[3][qt][2], st[3][qt][3]);
            float b0 = fmaxf(fmaxf(a0, a1), fmaxf(a2, a3));
            float b1 = fmaxf(fmaxf(a4, a5), fmaxf(a6, a7));
            float mx = fmaxf(b0, b1);
            mx = fmaxf(mx, __shfl_xor(mx, 16, 64));
            mx = fmaxf(mx, __shfl_xor(mx, 32, 64));

            // defer-rescale (T13): skip O-rescale while max growth <= 8.
            // acc already contains PV(t-1) (register dep on the MFMAs above).
            if (!__all(mx <= mrow[qt] + 8.f)) {
                const float mn    = fmaxf(mrow[qt], mx);
                const float alpha = __builtin_amdgcn_exp2f(mrow[qt] - mn);
                mrow[qt] = mn;
                lrow[qt] *= alpha;
                #pragma unroll
                for (int dt = 0; dt < 4; ++dt) {
                    acc[dt][qt][0] *= alpha; acc[dt][qt][1] *= alpha;
                    acc[dt][qt][2] *= alpha; acc[dt][qt][3] *= alpha;
                }
            }

            const int row = qt * 16 + c;
            #pragma unroll
            for (int kt = 0; kt < 4; ++kt) {
                u16x4 pb;
                #pragma unroll
                for (int r = 0; r < 4; ++r)
                    pb[r] = f2bf(__builtin_amdgcn_exp2f(st[kt][qt][r] - mrow[qt]));
                const int blk = (kt * 2 + (g >> 1)) ^ (row & 7);
                *reinterpret_cast<u16x4*>(pbase + row * 128 + blk * 16 + (g & 1) * 8) = pb;
            }
        }

        asm volatile("s_waitcnt lgkmcnt(0)" ::: "memory");

        // ---- P(t) fragments into registers (consumed next tile-step)
        #pragma unroll
        for (int qt = 0; qt < 2; ++qt) {
            const int row = qt * 16 + c;
            #pragma unroll
            for (int kh = 0; kh < 2; ++kh) {
                const int blk = (kh * 4 + g) ^ (row & 7);
                pfC[qt][kh] = *reinterpret_cast<const bf16x8*>(pbase + row * 128 + blk * 16);
            }
        }
        // row-sum of P(t) on the matrix pipe; read next tile-step
        #pragma unroll
        for (int qt = 0; qt < 2; ++qt) {
            suC[qt] = __builtin_amdgcn_mfma_f32_16x16x32_bf16(ones8, pfC[qt][0], zero4,   0, 0, 0);
            suC[qt] = __builtin_amdgcn_mfma_f32_16x16x32_bf16(ones8, pfC[qt][1], suC[qt], 0, 0, 0);
        }

        // ---- barrier: drains vmcnt (K stage of t+1, V frags of t) + lgkmcnt
        __syncthreads();
    };

    for (int tt = 0; tt < SEQL / 64; tt += 2) {
        body(vfA, pfA, suA, vfB, pfB, suB, tt,     tt != 0);
        body(vfB, pfB, suB, vfA, pfA, suA, tt + 1, true);
    }

    // ---- epilogue: final PV(31) + its row-sum, then normalize and store
    #pragma unroll
    for (int dt = 0; dt < 4; ++dt)
        #pragma unroll
        for (int qt = 0; qt < 2; ++qt) {
            acc[dt][qt] = __builtin_amdgcn_mfma_f32_16x16x32_bf16(vfB[dt*2],   pfB[qt][0], acc[dt][qt], 0, 0, 0);
            acc[dt][qt] = __builtin_amdgcn_mfma_f32_16x16x32_bf16(vfB[dt*2+1], pfB[qt][1], acc[dt][qt], 0, 0, 0);
        }
    lrow[0] += suB[0][0];
    lrow[1] += suB[1][0];

    const float inv0 = 1.f / lrow[0];
    const float inv1 = 1.f / lrow[1];
    #pragma unroll
    for (int qt = 0; qt < 2; ++qt) {
        const float inv = qt ? inv1 : inv0;
        float* op = out + ((size_t)b * SEQL + q0 + qt * 16 + c) * 1024 + h * 64 + g * 4;
        #pragma unroll
        for (int dt = 0; dt < 4; ++dt) {
            float4 o;
            o.x = acc[dt][qt][0] * inv; o.y = acc[dt][qt][1] * inv;
            o.z = acc[dt][qt][2] * inv; o.w = acc[dt][qt][3] * inv;
            *reinterpret_cast<float4*>(op + dt * 16) = o;
        }
    }
}

extern "C" void kernel_launch(void* const* d_in, const int* in_sizes, int n_in,
                              void* d_out, int out_size, void* d_ws, size_t ws_size,
                              hipStream_t stream) {
    const float* x  = (const float*)d_in[0];
    const float* Wq = (const float*)d_in[1];
    const float* bq = (const float*)d_in[2];
    const float* Wk = (const float*)d_in[3];
    const float* bk = (const float*)d_in[4];
    const float* Wv = (const float*)d_in[5];
    const float* bv = (const float*)d_in[6];
    float* out = (float*)d_out;

    const size_t per = (size_t)BHN * SEQL * 64;   // 4Mi elems per matrix
    u16* Qws = (u16*)d_ws;
    u16* Kws = Qws + per;
    u16* Vt  = Kws + per;
    u16* Wb  = Vt  + per;                         // 3*65536 bf16 = 384 KB

    wconv_kernel<<<dim3(64, 3), 256, 0, stream>>>(Wq, Wk, Wv, Wb);
    qkv_kernel<<<dim3(64, 16), 256, 0, stream>>>(x, Wb, bq, bk, bv, Qws, Kws, Vt);
    attn_kernel<<<dim3(512), 256, 0, stream>>>(Qws, Kws, Vt, out);
}

// Round 11
// 84.896 us; speedup vs baseline: 1.2120x; 1.2120x over previous
//
#include <hip/hip_runtime.h>

typedef unsigned short u16;
typedef unsigned int   u32;
typedef __bf16 bf16x8 __attribute__((ext_vector_type(8)));
typedef float  f32x4  __attribute__((ext_vector_type(4)));
typedef float  f32x16 __attribute__((ext_vector_type(16)));
typedef u16    u16x4  __attribute__((ext_vector_type(4)));
typedef u32    u32x4  __attribute__((ext_vector_type(4)));

#define HH   16
#define DHH  64
#define SEQL 2048
#define NB   2
#define BHN  (NB * HH)   // 32
#define SCLF 0.1803368801111204f   // 0.125 * log2(e)

static __device__ __forceinline__ u16 f2bf(float f) {
    return __builtin_bit_cast(u16, (__bf16)f);
}
static __device__ __forceinline__ u32 pack2(float a, float b) {
    return (u32)f2bf(a) | ((u32)f2bf(b) << 16);
}
// v_permlane32_swap_b32: dst.lanes[32:63] <-> src.lanes[0:31]
static __device__ __forceinline__ void plswap(u32 &a, u32 &b) {
    asm volatile("v_permlane32_swap_b32 %0, %1" : "+v"(a), "+v"(b));
}

// direct global->LDS DMA, 16B per lane; LDS dest = wave-uniform base + lane*16
static __device__ __forceinline__ void gload_lds16(const void* g, void* l) {
    __builtin_amdgcn_global_load_lds(
        (const __attribute__((address_space(1))) unsigned int*)g,
        (__attribute__((address_space(3))) unsigned int*)l, 16, 0, 0);
}

// ---------------------------------------------------------------------------
// Kernel 0: one-time W f32 -> bf16 pre-cast.  Wb layout: [m][h][e][d] bf16.
// Wq is pre-scaled by SCLF so QK^T lands directly in the exp2 domain.
// ---------------------------------------------------------------------------
__global__ __launch_bounds__(256) void wconv_kernel(
    const float* __restrict__ Wq, const float* __restrict__ Wk,
    const float* __restrict__ Wv, u16* __restrict__ Wb)
{
    const int m = blockIdx.y;
    const float* W = (m == 0) ? Wq : (m == 1) ? Wk : Wv;
    const float s = (m == 0) ? SCLF : 1.0f;
    const int i = (blockIdx.x * 256 + threadIdx.x) * 4;   // 65536 f32 per matrix
    float4 v = *reinterpret_cast<const float4*>(W + i);
    u16x4 o = { f2bf(v.x * s), f2bf(v.y * s), f2bf(v.z * s), f2bf(v.w * s) };
    *reinterpret_cast<u16x4*>(Wb + (size_t)m * 65536 + i) = o;
}

// ---------------------------------------------------------------------------
// Kernel 1: per-head QKV projection.  x[B,S,D] f32 -> Q,K bf16 [bh][S][64],
// V^T bf16 [bh][64][S].  One block = 64 rows x 1 head, 4 waves x 16 rows.
// All global stores coalesced 16B via the LDS repack tile.
// ---------------------------------------------------------------------------
__global__ __launch_bounds__(256) void qkv_kernel(
    const float* __restrict__ x, const u16* __restrict__ Wb,
    const float* __restrict__ bq, const float* __restrict__ bk,
    const float* __restrict__ bv,
    u16* __restrict__ Qws, u16* __restrict__ Kws, u16* __restrict__ Vtws)
{
    const int h   = blockIdx.y;
    const int r0  = blockIdx.x * 64;          // row in [0, B*S)
    const int tid = threadIdx.x;
    const int w   = tid >> 6;
    const int l   = tid & 63;
    const int c   = l & 15;
    const int g   = l >> 4;

    __shared__ u16 vt[64 * 72];               // repack tile (reused Q,K,V)

    bf16x8 xa[2];
    {
        const float* xp = x + (size_t)(r0 + w * 16 + c) * 1024 + h * 64 + g * 8;
        #pragma unroll
        for (int kh = 0; kh < 2; ++kh) {
            float4 lo = *reinterpret_cast<const float4*>(xp + kh * 32);
            float4 hi = *reinterpret_cast<const float4*>(xp + kh * 32 + 4);
            bf16x8 f;
            f[0]=(__bf16)lo.x; f[1]=(__bf16)lo.y; f[2]=(__bf16)lo.z; f[3]=(__bf16)lo.w;
            f[4]=(__bf16)hi.x; f[5]=(__bf16)hi.y; f[6]=(__bf16)hi.z; f[7]=(__bf16)hi.w;
            xa[kh] = f;
        }
    }

    const int b      = r0 >> 11;              // / SEQL
    const int s_base = r0 & (SEQL - 1);
    const int bh     = b * HH + h;

    const float* bs[3] = {bq + h * 64, bk + h * 64, bv + h * 64};

    #pragma unroll
    for (int m = 0; m < 3; ++m) {
        const u16*   W    = Wb + (size_t)m * 65536 + h * 4096;
        const float* bias = bs[m];
        const float  bscl = (m == 0) ? SCLF : 1.0f;
        f32x4 acc[4];
        #pragma unroll
        for (int ct = 0; ct < 4; ++ct) {
            acc[ct][0] = 0.f; acc[ct][1] = 0.f; acc[ct][2] = 0.f; acc[ct][3] = 0.f;
        }
        #pragma unroll
        for (int kh = 0; kh < 2; ++kh) {
            #pragma unroll
            for (int ct = 0; ct < 4; ++ct) {
                bf16x8 wf = *reinterpret_cast<const bf16x8*>(
                    W + (ct * 16 + c) * 64 + kh * 32 + g * 8);
                acc[ct] = __builtin_amdgcn_mfma_f32_16x16x32_bf16(xa[kh], wf, acc[ct], 0, 0, 0);
            }
        }
        // C layout: col(e) = ct*16+c, row(s within 16) = g*4 + r
        if (m < 2) {
            if (m == 1) __syncthreads();
            #pragma unroll
            for (int ct = 0; ct < 4; ++ct) {
                float bb = bias[ct * 16 + c] * bscl;
                #pragma unroll
                for (int r = 0; r < 4; ++r)
                    vt[(w * 16 + g * 4 + r) * 72 + ct * 16 + c] = f2bf(acc[ct][r] + bb);
            }
            __syncthreads();
            {
                const int d  = tid >> 2;
                const int s0 = (tid & 3) * 16;
                u16* outp = (m == 0 ? Qws : Kws) +
                            ((size_t)bh * SEQL + s_base + d) * 64 + s0;
                uint4 v0 = *reinterpret_cast<const uint4*>(&vt[d * 72 + s0]);
                uint4 v1 = *reinterpret_cast<const uint4*>(&vt[d * 72 + s0 + 8]);
                *reinterpret_cast<uint4*>(outp)     = v0;
                *reinterpret_cast<uint4*>(outp + 8) = v1;
            }
        } else {
            __syncthreads();
            #pragma unroll
            for (int ct = 0; ct < 4; ++ct) {
                float bb = bias[ct * 16 + c];
                u16x4 pb;
                #pragma unroll
                for (int r = 0; r < 4; ++r)
                    pb[r] = f2bf(acc[ct][r] + bb);
                *reinterpret_cast<u16x4*>(&vt[(ct * 16 + c) * 72 + w * 16 + g * 4]) = pb;
            }
            __syncthreads();
            {
                const int d  = tid >> 2;
                const int s0 = (tid & 3) * 16;
                u16* vp = Vtws + ((size_t)bh * 64 + d) * SEQL + s_base + s0;
                uint4 v0 = *reinterpret_cast<const uint4*>(&vt[d * 72 + s0]);
                uint4 v1 = *reinterpret_cast<const uint4*>(&vt[d * 72 + s0 + 8]);
                *reinterpret_cast<uint4*>(vp)     = v0;
                *reinterpret_cast<uint4*>(vp + 8) = v1;
            }
        }
    }
}

// ---------------------------------------------------------------------------
// Kernel 2: flash attention, 32x32 MFMA + in-register P (T12).
// One block = 128 q-rows of one (b,h); 4 waves x 32 q-rows.  Each lane owns
// q = q0 + (l&31).  S^T = K*Q^T via mfma_32x32x16 (C: col=q=l&31,
// key=(r&3)+8(r>>2)+4(l>>5)); softmax fully in-lane (+1 cross-half shfl);
// P packed to bf16 pairs and redistributed with v_permlane32_swap_b32 into
// PV B-fragments — no P LDS round-trip.  K/V double-buffered via
// global_load_lds (swizzled slots); T15 lag: PV(t-1) right after QK(t).
// ---------------------------------------------------------------------------
__global__ __launch_bounds__(256, 2) void attn_kernel(
    const u16* __restrict__ Qws, const u16* __restrict__ Kws,
    const u16* __restrict__ Vtws, float* __restrict__ out)
{
    // XCD-chunk swizzle: 512 blocks -> 64 consecutive logical blocks per XCD.
    const int p     = blockIdx.x;
    const int lid   = (p & 7) * 64 + (p >> 3);
    const int qtile = lid & 15;
    const int bh    = lid >> 4;
    const int b     = bh >> 4;
    const int h     = bh & 15;

    const int tid = threadIdx.x;
    const int w   = tid >> 6;
    const int l   = tid & 63;
    const int lq  = l & 31;                   // lane's q-row
    const int hi  = l >> 5;                   // lane half
    const int q0  = qtile * 128 + w * 32;

    __shared__ u16 k_lds[2][64 * 64];         // [buf][key_local][dh], swizzled
    __shared__ u16 v_lds[2][64 * 64];         // [buf][d][key_local], swizzled

    const u16* Kb = Kws  + (size_t)bh * SEQL * 64;
    const u16* Vb = Vtws + (size_t)bh * 64 * SEQL;

    const int rs8 = l >> 3;                   // 0..7
    const int sx  = (l & 7) ^ rs8;            // inverse-swizzled source slot

    #define STAGE(bb, k0)                                                     \
    {   _Pragma("unroll")                                                     \
        for (int a = 0; a < 2; ++a) {                                         \
            const int rbase = w * 16 + a * 8;                                 \
            const int r     = rbase + rs8;                                    \
            gload_lds16(Kb + (size_t)((k0) + r) * 64 + sx * 8,                \
                        &k_lds[bb][rbase * 64]);                              \
            gload_lds16(Vb + (size_t)r * SEQL + (k0) + sx * 8,                \
                        &v_lds[bb][rbase * 64]);                              \
        }                                                                     \
    }

    // Q fragments (B of S^T): Q[q0+lq][s*16 + hi*8 ..+8]
    bf16x8 qf[4];
    #pragma unroll
    for (int s = 0; s < 4; ++s)
        qf[s] = *reinterpret_cast<const bf16x8*>(
            Qws + ((size_t)bh * SEQL + q0 + lq) * 64 + s * 16 + hi * 8);

    f32x16 zero16;
    #pragma unroll
    for (int j = 0; j < 16; ++j) zero16[j] = 0.f;

    f32x16 acc[2];                            // O^T accum, d-tiles 0/1
    acc[0] = zero16; acc[1] = zero16;
    float mrow = -1e30f;
    float lrow = 0.f;

    // swizzled 16B slot offsets (bytes) within a 128B LDS row; row&7 == lq&7
    int koff[4];
    #pragma unroll
    for (int s = 0; s < 4; ++s) koff[s] = ((s * 2 + hi) ^ (lq & 7)) * 16;

    // A/B named prev-state (registers live across the barrier)
    bf16x8 vfA[2][4], vfB[2][4];
    bf16x8 pfA[4], pfB[4];

    STAGE(0, 0);
    __syncthreads();

    auto body = [&](bf16x8 (&vfC)[2][4], bf16x8 (&pfC)[4],
                    bf16x8 (&vfP)[2][4], bf16x8 (&pfP)[4],
                    int t, bool has_prev) {
        const int cur = t & 1;
        if (t + 1 < SEQL / 64) STAGE(cur ^ 1, (t + 1) * 64);

        // ---- K fragments (A of S^T): row = kt*32+lq, dh-slice s
        const char* kb = reinterpret_cast<const char*>(&k_lds[cur][0]);
        bf16x8 kf0[4], kf1[4];
        #pragma unroll
        for (int s = 0; s < 4; ++s) {
            kf0[s] = *reinterpret_cast<const bf16x8*>(kb + lq * 128 + koff[s]);
            kf1[s] = *reinterpret_cast<const bf16x8*>(kb + (32 + lq) * 128 + koff[s]);
        }

        __builtin_amdgcn_s_setprio(1);
        f32x16 st0 = __builtin_amdgcn_mfma_f32_32x32x16_bf16(kf0[0], qf[0], zero16, 0, 0, 0);
        f32x16 st1 = __builtin_amdgcn_mfma_f32_32x32x16_bf16(kf1[0], qf[0], zero16, 0, 0, 0);
        #pragma unroll
        for (int s = 1; s < 4; ++s) {
            st0 = __builtin_amdgcn_mfma_f32_32x32x16_bf16(kf0[s], qf[s], st0, 0, 0, 0);
            st1 = __builtin_amdgcn_mfma_f32_32x32x16_bf16(kf1[s], qf[s], st1, 0, 0, 0);
        }
        // ---- PV(t-1) from registers (overlaps the softmax below)
        if (has_prev) {
            #pragma unroll
            for (int s = 0; s < 4; ++s) {
                acc[0] = __builtin_amdgcn_mfma_f32_32x32x16_bf16(vfP[0][s], pfP[s], acc[0], 0, 0, 0);
                acc[1] = __builtin_amdgcn_mfma_f32_32x32x16_bf16(vfP[1][s], pfP[s], acc[1], 0, 0, 0);
            }
        }
        __builtin_amdgcn_s_setprio(0);

        // ---- V(t) fragments (A of PV): row d = dt*32+lq, key-slice s
        const char* vb = reinterpret_cast<const char*>(&v_lds[cur][0]);
        #pragma unroll
        for (int dt = 0; dt < 2; ++dt)
            #pragma unroll
            for (int s = 0; s < 4; ++s)
                vfC[dt][s] = *reinterpret_cast<const bf16x8*>(vb + (dt * 32 + lq) * 128 + koff[s]);

        // ---- softmax: in-lane over 32 keys + one cross-half shfl
        float t0 = fmaxf(fmaxf(st0[0], st0[1]),  fmaxf(st0[2], st0[3]));
        float t1 = fmaxf(fmaxf(st0[4], st0[5]),  fmaxf(st0[6], st0[7]));
        float t2 = fmaxf(fmaxf(st0[8], st0[9]),  fmaxf(st0[10], st0[11]));
        float t3 = fmaxf(fmaxf(st0[12], st0[13]), fmaxf(st0[14], st0[15]));
        float t4 = fmaxf(fmaxf(st1[0], st1[1]),  fmaxf(st1[2], st1[3]));
        float t5 = fmaxf(fmaxf(st1[4], st1[5]),  fmaxf(st1[6], st1[7]));
        float t6 = fmaxf(fmaxf(st1[8], st1[9]),  fmaxf(st1[10], st1[11]));
        float t7 = fmaxf(fmaxf(st1[12], st1[13]), fmaxf(st1[14], st1[15]));
        float mx = fmaxf(fmaxf(fmaxf(t0, t1), fmaxf(t2, t3)),
                         fmaxf(fmaxf(t4, t5), fmaxf(t6, t7)));
        mx = fmaxf(mx, __shfl_xor(mx, 32, 64));

        // defer-rescale (T13); acc already holds PV(t-1)
        if (!__all(mx <= mrow + 8.f)) {
            const float mn    = fmaxf(mrow, mx);
            const float alpha = __builtin_amdgcn_exp2f(mrow - mn);
            mrow = mn;
            lrow *= alpha;
            #pragma unroll
            for (int j = 0; j < 16; ++j) { acc[0][j] *= alpha; acc[1][j] *= alpha; }
        }

        // ---- exp2 + pack + permlane redistribution (P stays in registers)
        float rs0 = 0.f, rs1 = 0.f;
        u32 wd[16];
        {
            float pp[16];
            #pragma unroll
            for (int r = 0; r < 16; ++r) {
                pp[r] = __builtin_amdgcn_exp2f(st0[r] - mrow);
                if (r & 1) rs1 += pp[r]; else rs0 += pp[r];
            }
            #pragma unroll
            for (int j = 0; j < 8; ++j) wd[j] = pack2(pp[2 * j], pp[2 * j + 1]);
        }
        {
            float pp[16];
            #pragma unroll
            for (int r = 0; r < 16; ++r) {
                pp[r] = __builtin_amdgcn_exp2f(st1[r] - mrow);
                if (r & 1) rs1 += pp[r]; else rs0 += pp[r];
            }
            #pragma unroll
            for (int j = 0; j < 8; ++j) wd[8 + j] = pack2(pp[2 * j], pp[2 * j + 1]);
        }
        lrow += rs0 + rs1;

        plswap(wd[0],  wd[2]);  plswap(wd[1],  wd[3]);
        plswap(wd[4],  wd[6]);  plswap(wd[5],  wd[7]);
        plswap(wd[8],  wd[10]); plswap(wd[9],  wd[11]);
        plswap(wd[12], wd[14]); plswap(wd[13], wd[15]);

        #pragma unroll
        for (int s = 0; s < 4; ++s) {
            u32x4 tmp = { wd[s * 4 + 0], wd[s * 4 + 1], wd[s * 4 + 2], wd[s * 4 + 3] };
            pfC[s] = __builtin_bit_cast(bf16x8, tmp);
        }

        // ---- barrier: drains vmcnt (stage of t+1) and protects buf[cur]
        __syncthreads();
    };

    for (int tt = 0; tt < SEQL / 64; tt += 2) {
        body(vfA, pfA, vfB, pfB, tt,     tt != 0);
        body(vfB, pfB, vfA, pfA, tt + 1, true);
    }

    // ---- epilogue: final PV(31), combine halves of l, normalize, store
    #pragma unroll
    for (int s = 0; s < 4; ++s) {
        acc[0] = __builtin_amdgcn_mfma_f32_32x32x16_bf16(vfB[0][s], pfB[s], acc[0], 0, 0, 0);
        acc[1] = __builtin_amdgcn_mfma_f32_32x32x16_bf16(vfB[1][s], pfB[s], acc[1], 0, 0, 0);
    }
    const float inv = 1.f / (lrow + __shfl_xor(lrow, 32, 64));

    // O^T[d][q]: d = dt*32 + rg*8 + hi*4 + (r&3), q = q0+lq
    float* op = out + ((size_t)b * SEQL + q0 + lq) * 1024 + h * 64 + hi * 4;
    #pragma unroll
    for (int dt = 0; dt < 2; ++dt)
        #pragma unroll
        for (int rg = 0; rg < 4; ++rg) {
            float4 o;
            o.x = acc[dt][rg * 4 + 0] * inv;
            o.y = acc[dt][rg * 4 + 1] * inv;
            o.z = acc[dt][rg * 4 + 2] * inv;
            o.w = acc[dt][rg * 4 + 3] * inv;
            *reinterpret_cast<float4*>(op + dt * 32 + rg * 8) = o;
        }
}

extern "C" void kernel_launch(void* const* d_in, const int* in_sizes, int n_in,
                              void* d_out, int out_size, void* d_ws, size_t ws_size,
                              hipStream_t stream) {
    const float* x  = (const float*)d_in[0];
    const float* Wq = (const float*)d_in[1];
    const float* bq = (const float*)d_in[2];
    const float* Wk = (const float*)d_in[3];
    const float* bk = (const float*)d_in[4];
    const float* Wv = (const float*)d_in[5];
    const float* bv = (const float*)d_in[6];
    float* out = (float*)d_out;

    const size_t per = (size_t)BHN * SEQL * 64;   // 4Mi elems per matrix
    u16* Qws = (u16*)d_ws;
    u16* Kws = Qws + per;
    u16* Vt  = Kws + per;
    u16* Wb  = Vt  + per;                         // 3*65536 bf16 = 384 KB

    wconv_kernel<<<dim3(64, 3), 256, 0, stream>>>(Wq, Wk, Wv, Wb);
    qkv_kernel<<<dim3(64, 16), 256, 0, stream>>>(x, Wb, bq, bk, bv, Qws, Kws, Vt);
    attn_kernel<<<dim3(512), 256, 0, stream>>>(Qws, Kws, Vt, out);
}